// Round 12
// baseline (119.196 us; speedup 1.0000x reference)
//
#include <hip/hip_runtime.h>
#include <math.h>

// ---------------------------------------------------------------------------
// SimpleAttention via fp16 MFMA:
//   qk = x @ W_qk.T + b  ->  q (pre-scaled by 0.125*log2e), k  [B,H,N,D] fp16
//   out[b,n] = mean_h exp2(s'_nn) / sum_m exp2(s'_nm),  s' = q.k (log2 domain)
// B=4 N=2048 H=12 D=64 C=768
// ---------------------------------------------------------------------------

#define B_ 4
#define N_ 2048
#define H_ 12
#define D_ 64
#define C_ 768
#define TWO_C 1536
// SCALE * log2(e) = 0.125 * 1.4426950408889634
#define QSCALE 0.18033688011112043f

typedef _Float16 half8 __attribute__((ext_vector_type(8)));
typedef _Float16 half4 __attribute__((ext_vector_type(4)));
typedef float floatx4 __attribute__((ext_vector_type(4)));

#if __has_builtin(__builtin_amdgcn_exp2f)
#define EXP2(x) __builtin_amdgcn_exp2f(x)
#else
#define EXP2(x) exp2f(x)
#endif

__device__ __forceinline__ void gload_lds16(const _Float16* g, _Float16* l) {
  __builtin_amdgcn_global_load_lds(
      (const __attribute__((address_space(1))) void*)g,
      (__attribute__((address_space(3))) void*)l, 16, 0, 0);
}

// ------------- fp32 -> fp16 conversion (x and W) + zero d_out ---------------
#define NX4 1572864  // x floats/4
#define NW4 294912   // W floats/4
__global__ __launch_bounds__(256) void conv_kernel(const float* __restrict__ x,
                                                   const float* __restrict__ W,
                                                   _Float16* __restrict__ xh,
                                                   _Float16* __restrict__ wh,
                                                   float* __restrict__ outz) {
  int i = blockIdx.x * 256 + threadIdx.x;
  if (i < 2048) {  // zero the 8192-float output (attn accumulates into it)
    float4 z; z.x = 0.f; z.y = 0.f; z.z = 0.f; z.w = 0.f;
    ((float4*)outz)[i] = z;
  }
  const float* in;
  _Float16* out;
  int idx;
  if (i < NX4) {
    in = x; out = xh; idx = i;
  } else if (i < NX4 + NW4) {
    in = W; out = wh; idx = i - NX4;
  } else {
    return;
  }
  float4 v = ((const float4*)in)[idx];
  half4 o;
  o[0] = (_Float16)v.x; o[1] = (_Float16)v.y;
  o[2] = (_Float16)v.z; o[3] = (_Float16)v.w;
  ((half4*)out)[idx] = o;
}

// ---------------- proj: C = x @ W^T + b, scattered to q/k -------------------
// M=8192, N=1536, K=768. 128x128 tile, 4 waves (2x2), 16x16x32 f16 MFMA.
// Ring-3 LDS (48 KB), counted per-wave vmcnt + raw s_barrier: per iter wait
// vmcnt(4) = tile kt landed, kt+1 stays in flight; stage kt+2 after barrier.
// Chunk-XOR swizzle keeps ds_read 2-way (free).
__global__ __launch_bounds__(256) void proj_kernel(
    const _Float16* __restrict__ xh, const _Float16* __restrict__ wh,
    const float* __restrict__ bias, _Float16* __restrict__ qh,
    _Float16* __restrict__ kh) {
  __shared__ _Float16 As[3][128 * 32];
  __shared__ _Float16 Bs[3][128 * 32];
  const int t = threadIdx.x;
  const int l = t & 63;
  const int w = t >> 6;
  const int wr = w >> 1, wc = w & 1;

  // XCD-chunked bijective block swizzle (768 blocks % 8 == 0)
  int lin = blockIdx.y * 12 + blockIdx.x;
  int swz = (lin & 7) * 96 + (lin >> 3);
  const int bm = (swz / 12) * 128;
  const int bc = (swz % 12) * 128;

  // staging source: lane l covers (row = l>>2, stored chunk p = l&3);
  // global chunk to fetch = p ^ f(row), f(row) = (row>>1)&3 = (l>>3)&3
  const int srow = l >> 2;
  const int schunk = (l & 3) ^ ((l >> 3) & 3);

  floatx4 acc[4][4] = {};

#define PSTAGE(KT)                                                          \
  {                                                                         \
    const int sl_ = (KT) % 3;                                               \
    const int k0_ = (KT) * 32;                                              \
    _Pragma("unroll") for (int i_ = 0; i_ < 2; ++i_) {                      \
      int rb_ = w * 32 + i_ * 16;                                           \
      gload_lds16(xh + (size_t)(bm + rb_ + srow) * C_ + k0_ + schunk * 8,   \
                  As[sl_] + rb_ * 32);                                      \
      gload_lds16(wh + (size_t)(bc + rb_ + srow) * C_ + k0_ + schunk * 8,   \
                  Bs[sl_] + rb_ * 32);                                      \
    }                                                                       \
  }

#define PITER(KT, VMASM, DO_STAGE)                                          \
  {                                                                         \
    asm volatile(VMASM ::: "memory");                                       \
    __builtin_amdgcn_s_barrier();                                           \
    asm volatile("" ::: "memory");                                          \
    const int sl_ = (KT) % 3;                                               \
    const _Float16* Ap_ = As[sl_];                                          \
    const _Float16* Bp_ = Bs[sl_];                                          \
    half8 af[4], bf[4];                                                     \
    _Pragma("unroll") for (int fr = 0; fr < 4; ++fr) {                      \
      int row = wr * 64 + fr * 16 + (l & 15);                               \
      int ch = (l >> 4) ^ ((row >> 1) & 3);                                 \
      af[fr] = *(const half8*)(Ap_ + row * 32 + ch * 8);                    \
    }                                                                       \
    _Pragma("unroll") for (int fc = 0; fc < 4; ++fc) {                      \
      int row = wc * 64 + fc * 16 + (l & 15);                               \
      int ch = (l >> 4) ^ ((row >> 1) & 3);                                 \
      bf[fc] = *(const half8*)(Bp_ + row * 32 + ch * 8);                    \
    }                                                                       \
    if (DO_STAGE) PSTAGE((KT) + 2);                                         \
    _Pragma("unroll") for (int fr = 0; fr < 4; ++fr)                        \
        _Pragma("unroll") for (int fc = 0; fc < 4; ++fc) acc[fr][fc] =      \
        __builtin_amdgcn_mfma_f32_16x16x32_f16(af[fr], bf[fc],              \
                                               acc[fr][fc], 0, 0, 0);       \
  }

  PSTAGE(0);
  PSTAGE(1);
  for (int kt = 0; kt < 22; ++kt) PITER(kt, "s_waitcnt vmcnt(4)", true);
  PITER(22, "s_waitcnt vmcnt(4)", false);
  PITER(23, "s_waitcnt vmcnt(0)", false);
#undef PITER
#undef PSTAGE

  // epilogue: + bias, q pre-scaled by SCALE*log2e, scatter into [b,h,n,d]
#pragma unroll
  for (int fr = 0; fr < 4; ++fr) {
#pragma unroll
    for (int fc = 0; fc < 4; ++fc) {
#pragma unroll
      for (int j = 0; j < 4; ++j) {
        int m = bm + wr * 64 + fr * 16 + ((l >> 4) << 2) + j;
        int c = bc + wc * 64 + fc * 16 + (l & 15);
        float v = acc[fr][fc][j] + bias[c];
        int b = m >> 11, n = m & (N_ - 1);
        int cc = (c < C_) ? c : c - C_;
        if (c < C_) v *= QSCALE;
        int hh = cc >> 6, d = cc & 63;
        _Float16* dst = (c < C_) ? qh : kh;
        dst[((((size_t)b * H_ + hh) * N_ + n) << 6) + d] = (_Float16)v;
      }
    }
  }
}

// ---------------- attn: pair-phase via 8 waves (512 threads) ----------------
// Block = one (qt,h,b) 64-query tile, 8 waves. Per phase pm (16 phases) the
// block consumes a PAIR of 64-key tiles: waves 0-3 work tile A (cols w*16..),
// waves 4-7 tile B. Per-wave state identical to R6 (qf[4][2], 4 acc, ~56
// VGPR) -- pairing is on the wave axis, not the unroll axis (R10's mistake).
// Ring-4 pair-slots (64 KB) staged via global_load_lds; R6-proven discipline:
// prologue stages pairs 0-2, phase pm stages pm+3, per-wave vmcnt(4) steady
// state (2 pairs in flight), tail vmcnt(4)/(2)/(0). Barriers per key HALVED.
// Softmax in log2 domain; head-mean fused via atomicAdd.
__global__ __launch_bounds__(512) void attn_kernel(
    const _Float16* __restrict__ qh, const _Float16* __restrict__ kh,
    float* __restrict__ out) {
  __shared__ _Float16 ks[4][2][4096];  // 4 pair-slots x 2 tiles x 8 KB
  const int t = threadIdx.x;
  const int l = t & 63;
  const int w = t >> 6;       // 0..7
  const int wg = w & 3;       // col-slice within tile
  const int ts = w >> 2;      // tile side within pair

  // XCD-chunked swizzle: 192 consecutive work items per XCD = 6 (b,h) slabs
  int lin = blockIdx.x;
  int swz = (lin & 7) * 192 + (lin >> 3);
  const int qt = swz & 31;
  const int h = (swz >> 5) % 12;
  const int b = swz / 384;

  const _Float16* qb = qh + (((size_t)(b * H_ + h) * N_ + qt * 64) << 6);
  const _Float16* kb = kh + (((size_t)(b * H_ + h) * N_) << 6);

  // Q fragments: all 64 rows per wave. qf[fr][kd] covers row fr*16+(l&15),
  // k-chunk kd*32 + (l>>4)*8.
  half8 qf[4][2];
#pragma unroll
  for (int fr = 0; fr < 4; ++fr)
#pragma unroll
    for (int kd = 0; kd < 2; ++kd)
      qf[fr][kd] = *(const half8*)(qb + (size_t)(fr * 16 + (l & 15)) * 64 +
                                   kd * 32 + (l >> 4) * 8);

  // staging: 512 threads cover one 8 KB tile with one 16B gload each
  // (2 gloads/thread per pair). thread t -> tile pos row=t>>3, chunk slot=t&7;
  // global chunk = slot ^ (row&7); linear LDS dest = wave base + l*16B.
  const int srow = t >> 3, sslot = t & 7;
  const int soff = srow * 64 + (sslot ^ (srow & 7)) * 8;

#define SPAIR(PM)                                                      \
  {                                                                    \
    const _Float16* kp_ = kb + (size_t)(PM) * 8192;                    \
    gload_lds16(kp_ + soff, &ks[(PM) & 3][0][w * 512]);                \
    gload_lds16(kp_ + 4096 + soff, &ks[(PM) & 3][1][w * 512]);         \
  }

  // frag read offsets (swizzled): row = wg*16+(l&15) -> row&7 == l&7
  const int frow = wg * 16 + (l & 15);
  const int koff0 = frow * 64 + (((l >> 4) + 0) ^ (l & 7)) * 8;
  const int koff1 = frow * 64 + (((l >> 4) + 4) ^ (l & 7)) * 8;

  floatx4 lsum[4] = {};
  float ed[4] = {0.f, 0.f, 0.f, 0.f};
  const int pm_diag = qt >> 1;
  const bool diag_side = (ts == (qt & 1));

#define ITER(PM, VMASM, DO_STAGE)                                             \
  {                                                                           \
    asm volatile(VMASM ::: "memory");                                         \
    __builtin_amdgcn_s_barrier();                                             \
    asm volatile("" ::: "memory");                                            \
    const _Float16* bufp = &ks[(PM) & 3][ts][0];                              \
    half8 kf0 = *(const half8*)(bufp + koff0);                                \
    half8 kf1 = *(const half8*)(bufp + koff1);                                \
    if (DO_STAGE) SPAIR((PM) + 3);                                            \
    floatx4 acc[4] = {};                                                      \
    _Pragma("unroll") for (int fr = 0; fr < 4; ++fr) {                        \
      acc[fr] = __builtin_amdgcn_mfma_f32_16x16x32_f16(qf[fr][0], kf0,        \
                                                       acc[fr], 0, 0, 0);     \
      acc[fr] = __builtin_amdgcn_mfma_f32_16x16x32_f16(qf[fr][1], kf1,        \
                                                       acc[fr], 0, 0, 0);     \
    }                                                                         \
    _Pragma("unroll") for (int fr = 0; fr < 4; ++fr) {                        \
      floatx4 ev;                                                             \
      _Pragma("unroll") for (int j = 0; j < 4; ++j) ev[j] = EXP2(acc[fr][j]); \
      lsum[fr] += ev;                                                         \
    }                                                                         \
    if ((PM) == pm_diag && diag_side) {                                       \
      _Pragma("unroll") for (int fr = 0; fr < 4; ++fr)                        \
          _Pragma("unroll") for (int j = 0; j < 4; ++j) {                     \
        if (fr == wg && (l & 15) == (((l >> 4) << 2) + j))                    \
          ed[j] = EXP2(acc[fr][j]);                                           \
      }                                                                       \
    }                                                                         \
  }

  SPAIR(0);
  SPAIR(1);
  SPAIR(2);

  for (int pm = 0; pm < 13; ++pm) ITER(pm, "s_waitcnt vmcnt(4)", true);
  ITER(13, "s_waitcnt vmcnt(4)", false);
  ITER(14, "s_waitcnt vmcnt(2)", false);
  ITER(15, "s_waitcnt vmcnt(0)", false);
#undef ITER
#undef SPAIR

  // reduce over the 16 lanes of each col group (cols of this wave's slice)
#pragma unroll
  for (int fr = 0; fr < 4; ++fr)
#pragma unroll
    for (int j = 0; j < 4; ++j)
#pragma unroll
      for (int m = 1; m < 16; m <<= 1)
        lsum[fr][j] += __shfl_xor(lsum[fr][j], m, 16);
#pragma unroll
  for (int j = 0; j < 4; ++j)
#pragma unroll
    for (int m = 1; m < 16; m <<= 1) ed[j] += __shfl_xor(ed[j], m, 16);

  // cross-wave combine in LDS (slot0/tileA region, last read at phase 12),
  // then fused head-mean via atomicAdd. red[8][64] partials + edl[64].
  float* red = (float*)&ks[0][0][0];
  float* edl = red + 512;
  if ((l & 15) == 0) {
#pragma unroll
    for (int fr = 0; fr < 4; ++fr)
#pragma unroll
      for (int j = 0; j < 4; ++j)
        red[w * 64 + fr * 16 + ((l >> 4) << 2) + j] = lsum[fr][j];
    if (diag_side) {
#pragma unroll
      for (int j = 0; j < 4; ++j) edl[wg * 16 + ((l >> 4) << 2) + j] = ed[j];
    }
  }
  __syncthreads();

  if (t < 64) {
    float ls = 0.f;
#pragma unroll
    for (int i = 0; i < 8; ++i) ls += red[i * 64 + t];
    atomicAdd(out + (size_t)b * N_ + qt * 64 + t,
              edl[t] / ls * (1.0f / (float)H_));
  }
}

// ---------------------------------------------------------------------------
extern "C" void kernel_launch(void* const* d_in, const int* in_sizes, int n_in,
                              void* d_out, int out_size, void* d_ws,
                              size_t ws_size, hipStream_t stream) {
  const float* x = (const float*)d_in[0];
  const float* W = (const float*)d_in[1];
  const float* bias = (const float*)d_in[2];
  float* out = (float*)d_out;

  char* ws = (char*)d_ws;
  _Float16* xh = (_Float16*)ws;               // 8192*768 fp16
  _Float16* wh = (_Float16*)(ws + 12582912);  // 1536*768 fp16
  _Float16* qh = (_Float16*)(ws + 14942208);  // B*H*N*D fp16 (pre-scaled)
  _Float16* kh = (_Float16*)(ws + 27525120);  // B*H*N*D fp16

  conv_kernel<<<(NX4 + NW4 + 255) / 256, 256, 0, stream>>>(x, W, xh, wh, out);
  proj_kernel<<<dim3(TWO_C / 128, 8192 / 128), 256, 0, stream>>>(xh, wh, bias,
                                                                 qh, kh);
  attn_kernel<<<N_ / 64 * H_ * B_, 512, 0, stream>>>(qh, kh, out);
}

// Round 13
// 81.654 us; speedup vs baseline: 1.4598x; 1.4598x over previous
//
#include <hip/hip_runtime.h>
#include <math.h>

// ---------------------------------------------------------------------------
// SimpleAttention via fp16 MFMA:
//   qk = x @ W_qk.T + b  ->  q (pre-scaled by 0.125*log2e), k  [B,H,N,D] fp16
//   out[b,n] = mean_h exp2(s'_nn) / sum_m exp2(s'_nm),  s' = q.k (log2 domain)
// B=4 N=2048 H=12 D=64 C=768
// ---------------------------------------------------------------------------

#define B_ 4
#define N_ 2048
#define H_ 12
#define D_ 64
#define C_ 768
#define TWO_C 1536
// SCALE * log2(e) = 0.125 * 1.4426950408889634
#define QSCALE 0.18033688011112043f

typedef _Float16 half8 __attribute__((ext_vector_type(8)));
typedef _Float16 half4 __attribute__((ext_vector_type(4)));
typedef float floatx4 __attribute__((ext_vector_type(4)));

#if __has_builtin(__builtin_amdgcn_exp2f)
#define EXP2(x) __builtin_amdgcn_exp2f(x)
#else
#define EXP2(x) exp2f(x)
#endif

__device__ __forceinline__ void gload_lds16(const _Float16* g, _Float16* l) {
  __builtin_amdgcn_global_load_lds(
      (const __attribute__((address_space(1))) void*)g,
      (__attribute__((address_space(3))) void*)l, 16, 0, 0);
}

// ------------- fp32 -> fp16 conversion (x and W) + zero d_out ---------------
#define NX4 1572864  // x floats/4
#define NW4 294912   // W floats/4
__global__ __launch_bounds__(256) void conv_kernel(const float* __restrict__ x,
                                                   const float* __restrict__ W,
                                                   _Float16* __restrict__ xh,
                                                   _Float16* __restrict__ wh,
                                                   float* __restrict__ outz) {
  int i = blockIdx.x * 256 + threadIdx.x;
  if (i < 2048) {  // zero the 8192-float output (attn accumulates into it)
    float4 z; z.x = 0.f; z.y = 0.f; z.z = 0.f; z.w = 0.f;
    ((float4*)outz)[i] = z;
  }
  const float* in;
  _Float16* out;
  int idx;
  if (i < NX4) {
    in = x; out = xh; idx = i;
  } else if (i < NX4 + NW4) {
    in = W; out = wh; idx = i - NX4;
  } else {
    return;
  }
  float4 v = ((const float4*)in)[idx];
  half4 o;
  o[0] = (_Float16)v.x; o[1] = (_Float16)v.y;
  o[2] = (_Float16)v.z; o[3] = (_Float16)v.w;
  ((half4*)out)[idx] = o;
}

// ---------------- proj: C = x @ W^T + b, scattered to q/k -------------------
// M=8192, N=1536, K=768. 128x128 tile, 4 waves (2x2), 16x16x32 f16 MFMA.
// Ring-3 LDS (48 KB), counted per-wave vmcnt + raw s_barrier: per iter wait
// vmcnt(4) = tile kt landed, kt+1 stays in flight; stage kt+2 after barrier.
// Chunk-XOR swizzle keeps ds_read 2-way (free).
__global__ __launch_bounds__(256) void proj_kernel(
    const _Float16* __restrict__ xh, const _Float16* __restrict__ wh,
    const float* __restrict__ bias, _Float16* __restrict__ qh,
    _Float16* __restrict__ kh) {
  __shared__ _Float16 As[3][128 * 32];
  __shared__ _Float16 Bs[3][128 * 32];
  const int t = threadIdx.x;
  const int l = t & 63;
  const int w = t >> 6;
  const int wr = w >> 1, wc = w & 1;

  // XCD-chunked bijective block swizzle (768 blocks % 8 == 0)
  int lin = blockIdx.y * 12 + blockIdx.x;
  int swz = (lin & 7) * 96 + (lin >> 3);
  const int bm = (swz / 12) * 128;
  const int bc = (swz % 12) * 128;

  // staging source: lane l covers (row = l>>2, stored chunk p = l&3);
  // global chunk to fetch = p ^ f(row), f(row) = (row>>1)&3 = (l>>3)&3
  const int srow = l >> 2;
  const int schunk = (l & 3) ^ ((l >> 3) & 3);

  floatx4 acc[4][4] = {};

#define PSTAGE(KT)                                                          \
  {                                                                         \
    const int sl_ = (KT) % 3;                                               \
    const int k0_ = (KT) * 32;                                              \
    _Pragma("unroll") for (int i_ = 0; i_ < 2; ++i_) {                      \
      int rb_ = w * 32 + i_ * 16;                                           \
      gload_lds16(xh + (size_t)(bm + rb_ + srow) * C_ + k0_ + schunk * 8,   \
                  As[sl_] + rb_ * 32);                                      \
      gload_lds16(wh + (size_t)(bc + rb_ + srow) * C_ + k0_ + schunk * 8,   \
                  Bs[sl_] + rb_ * 32);                                      \
    }                                                                       \
  }

#define PITER(KT, VMASM, DO_STAGE)                                          \
  {                                                                         \
    asm volatile(VMASM ::: "memory");                                       \
    __builtin_amdgcn_s_barrier();                                           \
    asm volatile("" ::: "memory");                                          \
    const int sl_ = (KT) % 3;                                               \
    const _Float16* Ap_ = As[sl_];                                          \
    const _Float16* Bp_ = Bs[sl_];                                          \
    half8 af[4], bf[4];                                                     \
    _Pragma("unroll") for (int fr = 0; fr < 4; ++fr) {                      \
      int row = wr * 64 + fr * 16 + (l & 15);                               \
      int ch = (l >> 4) ^ ((row >> 1) & 3);                                 \
      af[fr] = *(const half8*)(Ap_ + row * 32 + ch * 8);                    \
    }                                                                       \
    _Pragma("unroll") for (int fc = 0; fc < 4; ++fc) {                      \
      int row = wc * 64 + fc * 16 + (l & 15);                               \
      int ch = (l >> 4) ^ ((row >> 1) & 3);                                 \
      bf[fc] = *(const half8*)(Bp_ + row * 32 + ch * 8);                    \
    }                                                                       \
    if (DO_STAGE) PSTAGE((KT) + 2);                                         \
    _Pragma("unroll") for (int fr = 0; fr < 4; ++fr)                        \
        _Pragma("unroll") for (int fc = 0; fc < 4; ++fc) acc[fr][fc] =      \
        __builtin_amdgcn_mfma_f32_16x16x32_f16(af[fr], bf[fc],              \
                                               acc[fr][fc], 0, 0, 0);       \
  }

  PSTAGE(0);
  PSTAGE(1);
  for (int kt = 0; kt < 22; ++kt) PITER(kt, "s_waitcnt vmcnt(4)", true);
  PITER(22, "s_waitcnt vmcnt(4)", false);
  PITER(23, "s_waitcnt vmcnt(0)", false);
#undef PITER
#undef PSTAGE

  // epilogue: + bias, q pre-scaled by SCALE*log2e, scatter into [b,h,n,d]
#pragma unroll
  for (int fr = 0; fr < 4; ++fr) {
#pragma unroll
    for (int fc = 0; fc < 4; ++fc) {
#pragma unroll
      for (int j = 0; j < 4; ++j) {
        int m = bm + wr * 64 + fr * 16 + ((l >> 4) << 2) + j;
        int c = bc + wc * 64 + fc * 16 + (l & 15);
        float v = acc[fr][fc][j] + bias[c];
        int b = m >> 11, n = m & (N_ - 1);
        int cc = (c < C_) ? c : c - C_;
        if (c < C_) v *= QSCALE;
        int hh = cc >> 6, d = cc & 63;
        _Float16* dst = (c < C_) ? qh : kh;
        dst[((((size_t)b * H_ + hh) * N_ + n) << 6) + d] = (_Float16)v;
      }
    }
  }
}

// ---------------- attn: diagonal softmax weight (R6/R11 structure) ----------
// Block = one (qt,h,b) 64-query tile, 4 waves. Wave w owns K-COL slice
// [w*16,w*16+16); Q frags for all 64 rows in registers. K tiles staged via
// global_load_lds into a RING-3 (24 KB -> 6 blocks/CU, perfect residency for
// the 1536-block grid); per iter:
//   s_waitcnt vmcnt(2) (tile kt landed; kt+1 IN FLIGHT) -> s_barrier ->
//   2 ds_read_b128 -> stage kt+2 -> setprio(1) 8 MFMA setprio(0) -> 16 exp2.
// Loop unrolled x3 so ring slots are compile-time. Softmax in log2 domain
// (q pre-scaled). Head-mean fused via atomicAdd.
__global__ __launch_bounds__(256) void attn_kernel(
    const _Float16* __restrict__ qh, const _Float16* __restrict__ kh,
    float* __restrict__ out) {
  __shared__ _Float16 ks[3][64 * 64];  // 24 KB ring
  const int t = threadIdx.x;
  const int l = t & 63;
  const int w = t >> 6;

  // XCD-chunked swizzle: 192 consecutive work items per XCD = 6 (b,h) slabs
  int lin = blockIdx.x;
  int swz = (lin & 7) * 192 + (lin >> 3);
  const int qt = swz & 31;
  const int h = (swz >> 5) % 12;
  const int b = swz / 384;

  const _Float16* qb = qh + (((size_t)(b * H_ + h) * N_ + qt * 64) << 6);
  const _Float16* kb = kh + (((size_t)(b * H_ + h) * N_) << 6);

  // Q fragments: all 64 rows per wave. qf[fr][kd] covers row fr*16+(l&15),
  // k-chunk kd*32 + (l>>4)*8.
  half8 qf[4][2];
#pragma unroll
  for (int fr = 0; fr < 4; ++fr)
#pragma unroll
    for (int kd = 0; kd < 2; ++kd)
      qf[fr][kd] = *(const half8*)(qb + (size_t)(fr * 16 + (l & 15)) * 64 +
                                   kd * 32 + (l >> 4) * 8);

  // staging: linear16 = w*64 + l (+256); row = lin>>3; slot = lin&7
  // global chunk = slot ^ (row&7)  (so swizzled data lands at linear dest)
  const int lin0 = w * 64 + l;
  const int row0 = lin0 >> 3, slot0 = lin0 & 7;
  const int soff0 = row0 * 64 + (slot0 ^ (row0 & 7)) * 8;
  const int lin1 = lin0 + 256;
  const int row1 = lin1 >> 3, slot1 = lin1 & 7;
  const int soff1 = row1 * 64 + (slot1 ^ (row1 & 7)) * 8;

#define STAGE(KT, SSLOT)                                            \
  {                                                                 \
    const _Float16* kp_ = kb + (size_t)(KT) * 4096;                 \
    _Float16* ld_ = ks[SSLOT];                                      \
    gload_lds16(kp_ + soff0, ld_ + w * 512);                        \
    gload_lds16(kp_ + soff1, ld_ + w * 512 + 2048);                 \
  }

  // frag read offsets (swizzled): row = w*16+(l&15), nominal chunk kd*4+(l>>4)
  const int frow = w * 16 + (l & 15);
  const int koff0 = frow * 64 + (((l >> 4) + 0) ^ (l & 7)) * 8;
  const int koff1 = frow * 64 + (((l >> 4) + 4) ^ (l & 7)) * 8;

  floatx4 lsum[4] = {};
  float ed[4] = {0.f, 0.f, 0.f, 0.f};

  STAGE(0, 0);
  STAGE(1, 1);

#define ITER(KT, SLOT, SSLOT, VMASM, DO_STAGE)                                \
  {                                                                           \
    asm volatile(VMASM ::: "memory");                                         \
    __builtin_amdgcn_s_barrier();                                             \
    asm volatile("" ::: "memory");                                            \
    const _Float16* bufp = ks[SLOT];                                          \
    half8 kf0 = *(const half8*)(bufp + koff0);                                \
    half8 kf1 = *(const half8*)(bufp + koff1);                                \
    if (DO_STAGE) STAGE((KT) + 2, SSLOT);                                     \
    floatx4 acc[4] = {};                                                      \
    __builtin_amdgcn_s_setprio(1);                                            \
    _Pragma("unroll") for (int fr = 0; fr < 4; ++fr) {                        \
      acc[fr] = __builtin_amdgcn_mfma_f32_16x16x32_f16(qf[fr][0], kf0,        \
                                                       acc[fr], 0, 0, 0);     \
      acc[fr] = __builtin_amdgcn_mfma_f32_16x16x32_f16(qf[fr][1], kf1,        \
                                                       acc[fr], 0, 0, 0);     \
    }                                                                         \
    __builtin_amdgcn_s_setprio(0);                                            \
    _Pragma("unroll") for (int fr = 0; fr < 4; ++fr) {                        \
      floatx4 ev;                                                             \
      _Pragma("unroll") for (int j = 0; j < 4; ++j) ev[j] = EXP2(acc[fr][j]); \
      lsum[fr] += ev;  /* f32x4 add -> packed adds */                         \
    }                                                                         \
    if ((KT) == qt) {                                                         \
      _Pragma("unroll") for (int fr = 0; fr < 4; ++fr)                        \
          _Pragma("unroll") for (int j = 0; j < 4; ++j) {                     \
        if (fr == w && (l & 15) == (((l >> 4) << 2) + j))                     \
          ed[j] = EXP2(acc[fr][j]);                                           \
      }                                                                       \
    }                                                                         \
  }

  // tiles 0..29 in groups of 3 (slots compile-time), staging kt+2 (<=31)
  for (int kt = 0; kt < 30; kt += 3) {
    ITER(kt + 0, 0, 2, "s_waitcnt vmcnt(2)", true);
    ITER(kt + 1, 1, 0, "s_waitcnt vmcnt(2)", true);
    ITER(kt + 2, 2, 1, "s_waitcnt vmcnt(2)", true);
  }
  ITER(30, 0, 0, "s_waitcnt vmcnt(2)", false);
  ITER(31, 1, 0, "s_waitcnt vmcnt(0)", false);
#undef ITER
#undef STAGE

  // reduce over the 16 lanes of each col group (cols of this wave's slice)
#pragma unroll
  for (int fr = 0; fr < 4; ++fr)
#pragma unroll
    for (int j = 0; j < 4; ++j)
#pragma unroll
      for (int m = 1; m < 16; m <<= 1)
        lsum[fr][j] += __shfl_xor(lsum[fr][j], m, 16);
#pragma unroll
  for (int j = 0; j < 4; ++j)
#pragma unroll
    for (int m = 1; m < 16; m <<= 1) ed[j] += __shfl_xor(ed[j], m, 16);

  // cross-wave combine in LDS, then fused head-mean via atomicAdd
  __builtin_amdgcn_s_barrier();  // all waves done with final frag reads
  float* red = (float*)ks[0];  // [4][64] lsum partials
  float* edl = red + 256;      // [64] diag exp (owned by exactly one wave)
  if ((l & 15) == 0) {
#pragma unroll
    for (int fr = 0; fr < 4; ++fr)
#pragma unroll
      for (int j = 0; j < 4; ++j)
        red[w * 64 + fr * 16 + ((l >> 4) << 2) + j] = lsum[fr][j];
#pragma unroll
    for (int j = 0; j < 4; ++j) edl[w * 16 + ((l >> 4) << 2) + j] = ed[j];
  }
  __syncthreads();

  if (t < 64) {
    float ls = red[t] + red[64 + t] + red[128 + t] + red[192 + t];
    atomicAdd(out + (size_t)b * N_ + qt * 64 + t,
              edl[t] / ls * (1.0f / (float)H_));
  }
}

// ---------------------------------------------------------------------------
extern "C" void kernel_launch(void* const* d_in, const int* in_sizes, int n_in,
                              void* d_out, int out_size, void* d_ws,
                              size_t ws_size, hipStream_t stream) {
  const float* x = (const float*)d_in[0];
  const float* W = (const float*)d_in[1];
  const float* bias = (const float*)d_in[2];
  float* out = (float*)d_out;

  char* ws = (char*)d_ws;
  _Float16* xh = (_Float16*)ws;               // 8192*768 fp16
  _Float16* wh = (_Float16*)(ws + 12582912);  // 1536*768 fp16
  _Float16* qh = (_Float16*)(ws + 14942208);  // B*H*N*D fp16 (pre-scaled)
  _Float16* kh = (_Float16*)(ws + 27525120);  // B*H*N*D fp16

  conv_kernel<<<(NX4 + NW4 + 255) / 256, 256, 0, stream>>>(x, W, xh, wh, out);
  proj_kernel<<<dim3(TWO_C / 128, 8192 / 128), 256, 0, stream>>>(xh, wh, bias,
                                                                 qh, kh);
  attn_kernel<<<N_ / 64 * H_ * B_, 256, 0, stream>>>(qh, kh, out);
}